// Round 14
// baseline (44.512 us; speedup 1.0000x reference)
//
#include <hip/hip_runtime.h>
#include <hip/hip_bf16.h>
#include <math.h>
#include <stdint.h>

#define B 8
#define L 256
#define DM 512
#define NH 16
#define APO 128
#define VOC 128
#define EMB (L * B * DM)   // 1048576 floats

typedef __attribute__((ext_vector_type(8))) short short8v;   // 8 bf16 (4 VGPR)
typedef __attribute__((ext_vector_type(4))) float float4v;   // MFMA C/D

// ws layout (main path):
//   float[0..255]    : unused (fallback-compat offsets)
//   float[256..1280) : wsB = lw' B-fragments, ushort[2048] (bf16, mfma frag layout)
//   byte 6144 ..     : packed table, 16384 rows x 512 B (32 pieces of 16B):
//                      chunk cc (16 k) = pieces [4cc,4cc+1]=w' halves, [4cc+2,4cc+3]=b'
//                      w' = w * beta/sigma_k ; b' = (b - mean_k) * beta/sigma_k  (bf16)
#define WSB_FOFF   256
#define PACK_BOFF  6144
#define PACK_BYTES (16384 * 512)
#define WS_NEED    ((size_t)PACK_BOFF + (size_t)PACK_BYTES)

__device__ __forceinline__ void g2lds16(const void* g, void* l) {
    __builtin_amdgcn_global_load_lds(
        (const __attribute__((address_space(1))) unsigned int*)g,
        (__attribute__((address_space(3))) unsigned int*)l, 16, 0, 0);
}

// ================= main path: setup (emb + table conversion + wsB) =============
__global__ __launch_bounds__(256) void setup_kernel(const int* __restrict__ atoms,
                                                    const int* __restrict__ chirals,
                                                    const float* __restrict__ atype,
                                                    const float* __restrict__ chiral,
                                                    const float* __restrict__ wtab,
                                                    const float* __restrict__ btab,
                                                    const float* __restrict__ means,
                                                    const float* __restrict__ stds,
                                                    const float* __restrict__ lin_w,
                                                    float* __restrict__ ws,
                                                    float* __restrict__ out) {
    int bid = blockIdx.x;          // 0..2047
    int t = threadIdx.x;
    const float beta = sqrtf(0.5f * 1.4426950408889634f);  // exp(-.5x^2)=exp2(-(x*beta)^2)
    const float gscale = 0.3989422804014327f;              // 1/sqrt(2*pi)

    // ---- emb for (bi,li) = bid (threads 0..127)
    if (t < 128) {
        int bi = bid >> 8, li = bid & 255;
        int a = atoms[bi * L + li];
        int c = chirals[bi * L + li];
        const float4* va = (const float4*)(atype + (size_t)a * DM);
        const float4* vc = (const float4*)(chiral + (size_t)c * DM);
        float4* vo = (float4*)(out + ((size_t)li * B + bi) * DM);
        float4 x = va[t], y = vc[t];
        x.x += y.x; x.y += y.y; x.z += y.z; x.w += y.w;
        vo[t] = x;
    }

    // ---- wsB (block 0): lw' in mfma_f32_16x16x32_bf16 B-frag layout
    if (bid == 0) {
        unsigned short* wsB = (unsigned short*)(ws + WSB_FOFF);
        for (int idx = t; idx < 4 * 64 * 8; idx += 256) {
            int c2 = idx >> 9;
            int lane = (idx >> 3) & 63;
            int e = idx & 7;
            int k = c2 * 32 + ((lane >> 4) << 3) + e;
            int h = lane & 15;
            float sigma = fabsf(stds[k]) + 1e-5f;
            float v = lin_w[k * NH + h] * (gscale / sigma);
            __hip_bfloat16 hb = __float2bfloat16(v);
            wsB[idx] = *reinterpret_cast<unsigned short*>(&hb);
        }
    }

    // ---- table conversion: one 16B piece (8 k) per thread
    int g = bid * 256 + t;          // 0..524287
    int row = g >> 5;               // 0..16383
    int p32 = g & 31;
    int cc = p32 >> 2, pp = p32 & 3;
    int k0 = cc * 16 + (pp & 1) * 8;
    const float* src = (pp < 2) ? wtab : btab;
    const float4* s4 = (const float4*)(src + (size_t)row * APO + k0);
    float4 v0 = s4[0], v1 = s4[1];
    const float* vv = (const float*)&v0;
    short8v o;
    #pragma unroll
    for (int e = 0; e < 8; ++e) {
        int k = k0 + e;
        float x = (e < 4) ? vv[e] : ((const float*)&v1)[e - 4];
        float sigma = fabsf(stds[k]) + 1e-5f;
        float ia = beta / sigma;
        float val = (pp < 2) ? x * ia : (x - means[k]) * ia;
        __hip_bfloat16 hb = __float2bfloat16(val);
        o[e] = *reinterpret_cast<short*>(&hb);
    }
    char* pk = (char*)ws + PACK_BOFF;
    *(short8v*)(pk + (size_t)row * 512 + cc * 64 + pp * 16) = o;
}

// ================= main path: pair kernel ======================================
// Row-universe staging, 4 passes x 32k, DOUBLE-BUFFERED (T3 minimal 2-phase):
// STAGE(p+1 -> other 16KB buf) issued BEFORE compute(p); __syncthreads()'s
// vmcnt(0) then waits for loads that flew under a whole compute pass. Only
// pass-0's stage is cold-exposed (hidden by 5 co-resident blocks/CU, LDS=32KB).
__global__ __launch_bounds__(256, 5) void pair_kernel_bf16(const int* __restrict__ atoms,
                                                           const float* __restrict__ coords,
                                                           const int* __restrict__ bonds,
                                                           const float* __restrict__ bond_emb,
                                                           const float* __restrict__ lin_b,
                                                           const float* __restrict__ ws,
                                                           float* __restrict__ out) {
    __shared__ __align__(16) char stage[32 * 1024];  // bufA = stage, bufB = stage+16K

    int t = threadIdx.x;            // j
    int bid = blockIdx.x;           // bi*256 + i
    int bi = bid >> 8, i = bid & 255;
    int w = t >> 6, l = t & 63;

    int a_i = atoms[bi * L + i];    // wave-uniform
    const char* pk = (const char*)ws + PACK_BOFF;
    char* bufA = stage;
    char* bufB = stage + 16384;

    // staging roles: instr 'it' covers rows [w*32+it*8, +8); lane l serves
    // row +(l>>3), LDS slot l&7 <- global local-piece (l&7)^(a&7) (involution).
    int s_rq = l >> 3, s_sl = l & 7;

#define STAGE_PASS(p, buf)                                                      \
    {                                                                           \
        _Pragma("unroll")                                                       \
        for (int it = 0; it < 4; ++it) {                                        \
            int a = w * 32 + it * 8 + s_rq;                                     \
            const char* g = pk + ((size_t)(a * VOC + a_i)) * 512                \
                            + (size_t)(p) * 128                                 \
                            + (size_t)((s_sl ^ (a & 7))) * 16;                  \
            g2lds16(g, (buf) + (size_t)(w * 32 + it * 8) * 128);                \
        }                                                                       \
    }

    // ---- pass-0 staging (cold; hidden by other resident blocks)
    STAGE_PASS(0, bufA)

    float cix = coords[((size_t)bi * L + i) * 3 + 0];
    float ciy = coords[((size_t)bi * L + i) * 3 + 1];
    float ciz = coords[((size_t)bi * L + i) * 3 + 2];
    float cjx = coords[((size_t)bi * L + t) * 3 + 0];
    float cjy = coords[((size_t)bi * L + t) * 3 + 1];
    float cjz = coords[((size_t)bi * L + t) * 3 + 2];
    float dx = cjx - cix, dy = cjy - ciy, dz = cjz - ciz;
    float s2 = dx * dx + dy * dy + dz * dz;
    float d = (s2 > 0.0f) ? sqrtf(s2) : 0.0f;

    // d of the 4 rows this lane's A-frags cover (wave-local lane r = row r)
    int dbits = __float_as_int(d);
    float dval[4];
    #pragma unroll
    for (int q = 0; q < 4; ++q)
        dval[q] = __int_as_float(
            __builtin_amdgcn_ds_bpermute((q * 16 + (l & 15)) * 4, dbits));

    // compute-side LDS offsets (pass-invariant): lane k-group m needs local
    // pieces pw (w) / pw+2 (b); slot = piece ^ (a&7); addr = a*128 + slot*16.
    int m = l >> 4;
    int pw = ((m >> 1) << 2) | (m & 1);         // {0,1,4,5}
    int woff[4], boff[4];
    #pragma unroll
    for (int q = 0; q < 4; ++q) {
        int jq = w * 64 + q * 16 + (l & 15);
        int a = atoms[bi * L + jq];
        int swz = a & 7;
        woff[q] = a * 128 + ((pw ^ swz) << 4);
        boff[q] = a * 128 + (((pw + 2) ^ swz) << 4);
    }

    const unsigned short* wsB = (const unsigned short*)(ws + WSB_FOFF);
    short8v bfrag[4];
    #pragma unroll
    for (int c2 = 0; c2 < 4; ++c2)
        bfrag[c2] = *(const short8v*)(wsB + ((size_t)c2 * 64 + l) * 8);

    float4v acc[4];
    #pragma unroll
    for (int q = 0; q < 4; ++q) { float4v z = {0, 0, 0, 0}; acc[q] = z; }

#define COMPUTE_PASS(rr, buf)                                                   \
    {                                                                           \
        _Pragma("unroll")                                                       \
        for (int q = 0; q < 4; ++q) {                                           \
            uint4 wv = *(const uint4*)((buf) + woff[q]);                        \
            uint4 bv = *(const uint4*)((buf) + boff[q]);                        \
            float dq = dval[q];                                                 \
            uint4 afu;                                                          \
            _Pragma("unroll")                                                   \
            for (int e2 = 0; e2 < 4; ++e2) {                                    \
                unsigned wd = ((const unsigned*)&wv)[e2];                       \
                unsigned bd = ((const unsigned*)&bv)[e2];                       \
                float wl = __uint_as_float(wd << 16);                           \
                float wh = __uint_as_float(wd & 0xffff0000u);                   \
                float bl = __uint_as_float(bd << 16);                           \
                float bh = __uint_as_float(bd & 0xffff0000u);                   \
                float tl = fmaf(wl, dq, bl);                                    \
                float th = fmaf(wh, dq, bh);                                    \
                float gl = __builtin_amdgcn_exp2f(-(tl * tl));                  \
                float gh = __builtin_amdgcn_exp2f(-(th * th));                  \
                unsigned glb = __float_as_uint(gl) + 0x8000u;                   \
                unsigned ghb = __float_as_uint(gh) + 0x8000u;                   \
                ((unsigned*)&afu)[e2] = (ghb & 0xffff0000u) | (glb >> 16);      \
            }                                                                   \
            short8v af = *reinterpret_cast<short8v*>(&afu);                     \
            acc[q] = __builtin_amdgcn_mfma_f32_16x16x32_bf16(af, bfrag[rr],     \
                                                             acc[q], 0, 0, 0); \
        }                                                                       \
    }

    asm volatile("s_waitcnt vmcnt(0)" ::: "memory");
    __syncthreads();                 // pass-0 rows ready

    STAGE_PASS(1, bufB)              // flies under compute 0
    COMPUTE_PASS(0, bufA)
    __syncthreads();                 // drains vmcnt(0): stage-1 landed

    STAGE_PASS(2, bufA)              // flies under compute 1
    COMPUTE_PASS(1, bufB)
    __syncthreads();

    STAGE_PASS(3, bufB)              // flies under compute 2
    COMPUTE_PASS(2, bufA)
    __syncthreads();

    COMPUTE_PASS(3, bufB)
    asm volatile("s_waitcnt lgkmcnt(0)" ::: "memory");
    __syncthreads();                 // all reads done -> reuse stage as cbuf
#undef COMPUTE_PASS
#undef STAGE_PASS

    // ---- epilogue: transpose C through reused staging LDS.
    // C layout (m89): col h = l&15, row j = 16q + (l>>4)*4 + reg.
    int a_j = atoms[bi * L + t];
    int bvd = bonds[(((size_t)bi * L) + i) * L + t];
    float beh[NH];
    {
        const float4* ber = (const float4*)(bond_emb + (size_t)bvd * NH);
        #pragma unroll
        for (int u = 0; u < 4; ++u) {
            float4 v4 = ber[u];
            beh[u * 4 + 0] = v4.x; beh[u * 4 + 1] = v4.y;
            beh[u * 4 + 2] = v4.z; beh[u * 4 + 3] = v4.w;
        }
    }
    float* cbuf = (float*)(stage + (size_t)w * 4352);   // 16 x 68 floats/wave
    {
        int h = l & 15, jg = l >> 4;
        #pragma unroll
        for (int q = 0; q < 4; ++q)
            *(float4v*)(cbuf + h * 68 + q * 16 + jg * 4) = acc[q];
    }
    asm volatile("s_waitcnt lgkmcnt(0)" ::: "memory");
    __builtin_amdgcn_sched_barrier(0);

    size_t obase = (((size_t)bi * NH) * L + i) * L + t;
    // PAD column -> most-negative FINITE bf16 (0xff7f0000); survives harness bf16 cast.
    float ninf = __uint_as_float(0xff7f0000u);
    bool pad = (a_j == 0);
    #pragma unroll
    for (int h = 0; h < NH; ++h) {
        float v = cbuf[h * 68 + l] + lin_b[h] + beh[h];
        out[obase + (size_t)h * L * L] = pad ? ninf : v;
    }
}

// ================= fallback path (r6, verified) ================================
__global__ __launch_bounds__(128) void emb_kernel(const int* __restrict__ atoms,
                                                  const int* __restrict__ chirals,
                                                  const float* __restrict__ atype,
                                                  const float* __restrict__ chiral,
                                                  float* __restrict__ out) {
    int bid = blockIdx.x;
    int bi = bid >> 8, li = bid & 255;
    int a = atoms[bi * L + li];
    int c = chirals[bi * L + li];
    const float4* va = (const float4*)(atype + (size_t)a * DM);
    const float4* vc = (const float4*)(chiral + (size_t)c * DM);
    float4* vo = (float4*)(out + ((size_t)li * B + bi) * DM);
    int t = threadIdx.x;
    float4 x = va[t], y = vc[t];
    x.x += y.x; x.y += y.y; x.z += y.z; x.w += y.w;
    vo[t] = x;
}

__global__ __launch_bounds__(256) void prep_kernel(const float* __restrict__ means,
                                                   const float* __restrict__ stds,
                                                   const float* __restrict__ lin_w,
                                                   float* __restrict__ ws) {
    int t = threadIdx.x;
    const float beta = sqrtf(0.5f * 1.4426950408889634f);
    const float gscale = 0.3989422804014327f;
    if (t < APO) {
        float sigma = fabsf(stds[t]) + 1e-5f;
        float inv = 1.0f / sigma;
        ws[t] = inv * beta;
        ws[APO + t] = -means[t] * inv * beta;
    }
    unsigned short* wsB = (unsigned short*)(ws + 2 * APO);
    for (int idx = t; idx < 4 * 64 * 8; idx += 256) {
        int c2 = idx >> 9;
        int lane = (idx >> 3) & 63;
        int e = idx & 7;
        int k = c2 * 32 + ((lane >> 4) << 3) + e;
        int h = lane & 15;
        float sigma = fabsf(stds[k]) + 1e-5f;
        float v = lin_w[k * NH + h] * (gscale / sigma);
        __hip_bfloat16 hb = __float2bfloat16(v);
        wsB[idx] = *reinterpret_cast<unsigned short*>(&hb);
    }
}

__global__ __launch_bounds__(256) void pair_kernel_f32(const int* __restrict__ atoms,
                                                       const float* __restrict__ coords,
                                                       const int* __restrict__ bonds,
                                                       const float* __restrict__ wtab,
                                                       const float* __restrict__ btab,
                                                       const float* __restrict__ bond_emb,
                                                       const float* __restrict__ lin_b,
                                                       const float* __restrict__ ws,
                                                       float* __restrict__ out) {
    __shared__ float be[32][17];
    __shared__ __align__(16) char lds_raw[32 * 1024];
    __shared__ __align__(16) char lds_g[16 * 1024];

    int t = threadIdx.x;
    int bid = blockIdx.x;
    int bi = bid >> 8, i = bid & 255;
    int w = t >> 6, l = t & 63;

    for (int idx = t; idx < 32 * NH; idx += 256)
        be[idx >> 4][idx & 15] = bond_emb[idx];
    __syncthreads();

    int a_i = atoms[bi * L + i];
    int a_j = atoms[bi * L + t];

    float cix = coords[((size_t)bi * L + i) * 3 + 0];
    float ciy = coords[((size_t)bi * L + i) * 3 + 1];
    float ciz = coords[((size_t)bi * L + i) * 3 + 2];
    float cjx = coords[((size_t)bi * L + t) * 3 + 0];
    float cjy = coords[((size_t)bi * L + t) * 3 + 1];
    float cjz = coords[((size_t)bi * L + t) * 3 + 2];
    float dx = cjx - cix, dy = cjy - ciy, dz = cjz - ciz;
    float s2 = dx * dx + dy * dy + dz * dz;
    float d = (s2 > 0.0f) ? sqrtf(s2) : 0.0f;

    char* ldsW = lds_raw + (size_t)w * 8192;
    char* ldsB_ = ldsW + 4096;
    char* gbase = lds_g + (size_t)w * 4096;
    const char* wt = (const char*)wtab;
    const char* bt = (const char*)btab;
    size_t goff[4];
    #pragma unroll
    for (int q = 0; q < 4; ++q) {
        int r = q * 16 + (l >> 2);
        int ajr = atoms[bi * L + (w * 64 + r)];
        int row = ajr * VOC + a_i;
        int piece = (l & 3) ^ ((r >> 1) & 3);
        goff[q] = (size_t)row * (APO * 4) + (size_t)piece * 16;
    }
    int ss = (l >> 1) & 3;

    const float* ia = ws;
    const float* c2c = ws + APO;
    const unsigned short* wsB = (const unsigned short*)(ws + 2 * APO);
    short8v bfrag[4];
    #pragma unroll
    for (int c2 = 0; c2 < 4; ++c2)
        bfrag[c2] = *(const short8v*)(wsB + ((size_t)c2 * 64 + l) * 8);

    float4v acc[4];
    #pragma unroll
    for (int q = 0; q < 4; ++q) { float4v z = {0,0,0,0}; acc[q] = z; }

    #pragma unroll
    for (int c2i = 0; c2i < 4; ++c2i) {
        short8v g8[4];
        #pragma unroll
        for (int s = 0; s < 2; ++s) {
            int cc = c2i * 2 + s;
            #pragma unroll
            for (int q = 0; q < 4; ++q) {
                g2lds16(wt + goff[q] + cc * 64, ldsW + q * 1024);
                g2lds16(bt + goff[q] + cc * 64, ldsB_ + q * 1024);
            }
            asm volatile("s_waitcnt vmcnt(0)" ::: "memory");
            __builtin_amdgcn_sched_barrier(0);
            #pragma unroll
            for (int p = 0; p < 4; ++p) {
                int u = p ^ ss;
                float4 w4 = *(const float4*)(ldsW + l * 64 + u * 16);
                float4 b4 = *(const float4*)(ldsB_ + l * 64 + u * 16);
                const float* wp = (const float*)&w4;
                const float* bp = (const float*)&b4;
                #pragma unroll
                for (int uu = 0; uu < 4; ++uu) {
                    int kk = s * 16 + p * 4 + uu;
                    int k = c2i * 32 + kk;
                    float tt = fmaf(wp[uu], d, bp[uu]);
                    tt = fmaf(tt, ia[k], c2c[k]);
                    float g = __builtin_amdgcn_exp2f(-(tt * tt));
                    __hip_bfloat16 hb = __float2bfloat16(g);
                    g8[kk >> 3][kk & 7] = *reinterpret_cast<short*>(&hb);
                }
            }
            asm volatile("s_waitcnt lgkmcnt(0)" ::: "memory");
            __builtin_amdgcn_sched_barrier(0);
        }
        int gswz = (l >> 1) & 3;
        #pragma unroll
        for (int kg = 0; kg < 4; ++kg)
            *(short8v*)(gbase + l * 64 + ((kg ^ gswz) * 16)) = g8[kg];
        asm volatile("s_waitcnt lgkmcnt(0)" ::: "memory");
        __builtin_amdgcn_sched_barrier(0);
        #pragma unroll
        for (int q = 0; q < 4; ++q) {
            int row = q * 16 + (l & 15);
            int kgr = (l >> 4) ^ ((row >> 1) & 3);
            short8v afrag = *(const short8v*)(gbase + row * 64 + kgr * 16);
            acc[q] = __builtin_amdgcn_mfma_f32_16x16x32_bf16(afrag, bfrag[c2i], acc[q], 0, 0, 0);
        }
        asm volatile("s_waitcnt lgkmcnt(0)" ::: "memory");
        __builtin_amdgcn_sched_barrier(0);
    }

    float* cbuf = (float*)ldsW;
    {
        int h = l & 15, jg = l >> 4;
        #pragma unroll
        for (int q = 0; q < 4; ++q)
            *(float4v*)(cbuf + h * 68 + q * 16 + jg * 4) = acc[q];
    }
    asm volatile("s_waitcnt lgkmcnt(0)" ::: "memory");
    __builtin_amdgcn_sched_barrier(0);

    size_t obase = (((size_t)bi * NH) * L + i) * L + t;
    int bv = bonds[(((size_t)bi * L) + i) * L + t];
    float ninf = __uint_as_float(0xff7f0000u);
    bool pad = (a_j == 0);
    #pragma unroll
    for (int h = 0; h < NH; ++h) {
        float v = cbuf[h * 68 + l] + lin_b[h] + be[bv][h];
        out[obase + (size_t)h * L * L] = pad ? ninf : v;
    }
}

extern "C" void kernel_launch(void* const* d_in, const int* in_sizes, int n_in,
                              void* d_out, int out_size, void* d_ws, size_t ws_size,
                              hipStream_t stream) {
    const int*   atoms    = (const int*)d_in[0];
    const int*   chirals  = (const int*)d_in[1];
    const float* coords   = (const float*)d_in[2];
    const int*   bonds    = (const int*)d_in[3];
    const float* atype    = (const float*)d_in[4];
    const float* chiral   = (const float*)d_in[5];
    const float* wtab     = (const float*)d_in[6];
    const float* btab     = (const float*)d_in[7];
    const float* means    = (const float*)d_in[8];
    const float* stds     = (const float*)d_in[9];
    const float* bond_emb = (const float*)d_in[10];
    const float* lin_w    = (const float*)d_in[11];
    const float* lin_b    = (const float*)d_in[12];
    float* out = (float*)d_out;
    float* ws  = (float*)d_ws;

    if (ws_size >= WS_NEED) {
        setup_kernel<<<B * L, 256, 0, stream>>>(atoms, chirals, atype, chiral, wtab, btab,
                                                means, stds, lin_w, ws, out);
        pair_kernel_bf16<<<B * L, 256, 0, stream>>>(atoms, coords, bonds, bond_emb,
                                                    lin_b, ws, out + (size_t)EMB);
    } else {
        prep_kernel<<<1, 256, 0, stream>>>(means, stds, lin_w, ws);
        emb_kernel<<<B * L, 128, 0, stream>>>(atoms, chirals, atype, chiral, out);
        pair_kernel_f32<<<B * L, 256, 0, stream>>>(atoms, coords, bonds, wtab, btab,
                                                   bond_emb, lin_b, ws, out + (size_t)EMB);
    }
}

// Round 15
// 41.935 us; speedup vs baseline: 1.0615x; 1.0615x over previous
//
#include <hip/hip_runtime.h>
#include <hip/hip_bf16.h>
#include <hip/hip_fp16.h>
#include <math.h>
#include <stdint.h>

#define B 8
#define L 256
#define DM 512
#define NH 16
#define APO 128
#define VOC 128
#define EMB (L * B * DM)   // 1048576 floats

typedef __attribute__((ext_vector_type(8))) short short8v;      // 8×16b (4 VGPR)
typedef __attribute__((ext_vector_type(8))) _Float16 half8v;    // 8 f16 (4 VGPR)
typedef __attribute__((ext_vector_type(4))) float float4v;      // MFMA C/D

// ws layout (main path):
//   float[0..255]    : unused (fallback-compat offsets)
//   float[256..1280) : wsB = lw' B-fragments, ushort[2048] (f16, mfma frag layout)
//   byte 6144 ..     : packed table, 16384 rows x 512 B (32 pieces of 16B), f16:
//                      chunk cc (16 k) = pieces [4cc,4cc+1]=w' halves, [4cc+2,4cc+3]=b'
//                      w' = w * beta/sigma_k ; b' = (b - mean_k) * beta/sigma_k
#define WSB_FOFF   256
#define PACK_BOFF  6144
#define PACK_BYTES (16384 * 512)
#define WS_NEED    ((size_t)PACK_BOFF + (size_t)PACK_BYTES)

__device__ __forceinline__ void g2lds16(const void* g, void* l) {
    __builtin_amdgcn_global_load_lds(
        (const __attribute__((address_space(1))) unsigned int*)g,
        (__attribute__((address_space(3))) unsigned int*)l, 16, 0, 0);
}

// ================= main path: setup (emb + table conversion + wsB) =============
__global__ __launch_bounds__(256) void setup_kernel(const int* __restrict__ atoms,
                                                    const int* __restrict__ chirals,
                                                    const float* __restrict__ atype,
                                                    const float* __restrict__ chiral,
                                                    const float* __restrict__ wtab,
                                                    const float* __restrict__ btab,
                                                    const float* __restrict__ means,
                                                    const float* __restrict__ stds,
                                                    const float* __restrict__ lin_w,
                                                    float* __restrict__ ws,
                                                    float* __restrict__ out) {
    int bid = blockIdx.x;          // 0..2047
    int t = threadIdx.x;
    const float beta = sqrtf(0.5f * 1.4426950408889634f);  // exp(-.5x^2)=exp2(-(x*beta)^2)
    const float gscale = 0.3989422804014327f;              // 1/sqrt(2*pi)

    // ---- emb for (bi,li) = bid (threads 0..127)
    if (t < 128) {
        int bi = bid >> 8, li = bid & 255;
        int a = atoms[bi * L + li];
        int c = chirals[bi * L + li];
        const float4* va = (const float4*)(atype + (size_t)a * DM);
        const float4* vc = (const float4*)(chiral + (size_t)c * DM);
        float4* vo = (float4*)(out + ((size_t)li * B + bi) * DM);
        float4 x = va[t], y = vc[t];
        x.x += y.x; x.y += y.y; x.z += y.z; x.w += y.w;
        vo[t] = x;
    }

    // ---- wsB (block 0): lw' (f16) in mfma_f32_16x16x32_f16 B-frag layout
    if (bid == 0) {
        unsigned short* wsB = (unsigned short*)(ws + WSB_FOFF);
        for (int idx = t; idx < 4 * 64 * 8; idx += 256) {
            int c2 = idx >> 9;
            int lane = (idx >> 3) & 63;
            int e = idx & 7;
            int k = c2 * 32 + ((lane >> 4) << 3) + e;
            int h = lane & 15;
            float sigma = fabsf(stds[k]) + 1e-5f;
            float v = lin_w[k * NH + h] * (gscale / sigma);
            __half hv = __float2half(v);
            wsB[idx] = *reinterpret_cast<unsigned short*>(&hv);
        }
    }

    // ---- table conversion: one 16B piece (8 k) per thread, f32 -> f16
    int g = bid * 256 + t;          // 0..524287
    int row = g >> 5;               // 0..16383
    int p32 = g & 31;
    int cc = p32 >> 2, pp = p32 & 3;
    int k0 = cc * 16 + (pp & 1) * 8;
    const float* src = (pp < 2) ? wtab : btab;
    const float4* s4 = (const float4*)(src + (size_t)row * APO + k0);
    float4 v0 = s4[0], v1 = s4[1];
    const float* vv = (const float*)&v0;
    short8v o;
    #pragma unroll
    for (int e = 0; e < 8; ++e) {
        int k = k0 + e;
        float x = (e < 4) ? vv[e] : ((const float*)&v1)[e - 4];
        float sigma = fabsf(stds[k]) + 1e-5f;
        float ia = beta / sigma;
        float val = (pp < 2) ? x * ia : (x - means[k]) * ia;
        __half hv = __float2half(val);
        o[e] = *reinterpret_cast<short*>(&hv);
    }
    char* pk = (char*)ws + PACK_BOFF;
    *(short8v*)(pk + (size_t)row * 512 + cc * 64 + pp * 16) = o;
}

// ================= main path: pair kernel ======================================
// r14-verified row-universe double-buffered staging, with the gauss pipeline in
// f16 packed math: __hfma2 (1 op/2 vals) + __hmul2(-t) + h2exp2 -> the half2
// dword IS the MFMA A-frag dword (no repack). mfma f16 = bf16 rate, same layout.
__global__ __launch_bounds__(256, 5) void pair_kernel_bf16(const int* __restrict__ atoms,
                                                           const float* __restrict__ coords,
                                                           const int* __restrict__ bonds,
                                                           const float* __restrict__ bond_emb,
                                                           const float* __restrict__ lin_b,
                                                           const float* __restrict__ ws,
                                                           float* __restrict__ out) {
    __shared__ __align__(16) char stage[32 * 1024];  // bufA = stage, bufB = stage+16K

    int t = threadIdx.x;            // j
    int bid = blockIdx.x;           // bi*256 + i
    int bi = bid >> 8, i = bid & 255;
    int w = t >> 6, l = t & 63;

    int a_i = atoms[bi * L + i];    // wave-uniform
    const char* pk = (const char*)ws + PACK_BOFF;
    char* bufA = stage;
    char* bufB = stage + 16384;

    // staging roles: instr 'it' covers rows [w*32+it*8, +8); lane l serves
    // row +(l>>3), LDS slot l&7 <- global local-piece (l&7)^(a&7) (involution).
    int s_rq = l >> 3, s_sl = l & 7;

#define STAGE_PASS(p, buf)                                                      \
    {                                                                           \
        _Pragma("unroll")                                                       \
        for (int it = 0; it < 4; ++it) {                                        \
            int a = w * 32 + it * 8 + s_rq;                                     \
            const char* g = pk + ((size_t)(a * VOC + a_i)) * 512                \
                            + (size_t)(p) * 128                                 \
                            + (size_t)((s_sl ^ (a & 7))) * 16;                  \
            g2lds16(g, (buf) + (size_t)(w * 32 + it * 8) * 128);                \
        }                                                                       \
    }

    // ---- pass-0 staging (cold; hidden by other resident blocks)
    STAGE_PASS(0, bufA)

    float cix = coords[((size_t)bi * L + i) * 3 + 0];
    float ciy = coords[((size_t)bi * L + i) * 3 + 1];
    float ciz = coords[((size_t)bi * L + i) * 3 + 2];
    float cjx = coords[((size_t)bi * L + t) * 3 + 0];
    float cjy = coords[((size_t)bi * L + t) * 3 + 1];
    float cjz = coords[((size_t)bi * L + t) * 3 + 2];
    float dx = cjx - cix, dy = cjy - ciy, dz = cjz - ciz;
    float s2 = dx * dx + dy * dy + dz * dz;
    float d = (s2 > 0.0f) ? sqrtf(s2) : 0.0f;

    // d of the 4 rows this lane's A-frags cover (wave-local lane r = row r)
    int dbits = __float_as_int(d);
    __half2 d2v[4];
    #pragma unroll
    for (int q = 0; q < 4; ++q) {
        float dq = __int_as_float(
            __builtin_amdgcn_ds_bpermute((q * 16 + (l & 15)) * 4, dbits));
        d2v[q] = __float2half2_rn(dq);
    }

    // compute-side LDS offsets (pass-invariant): lane k-group m needs local
    // pieces pw (w) / pw+2 (b); slot = piece ^ (a&7); addr = a*128 + slot*16.
    int m = l >> 4;
    int pw = ((m >> 1) << 2) | (m & 1);         // {0,1,4,5}
    int woff[4], boff[4];
    #pragma unroll
    for (int q = 0; q < 4; ++q) {
        int jq = w * 64 + q * 16 + (l & 15);
        int a = atoms[bi * L + jq];
        int swz = a & 7;
        woff[q] = a * 128 + ((pw ^ swz) << 4);
        boff[q] = a * 128 + (((pw + 2) ^ swz) << 4);
    }

    const unsigned short* wsB = (const unsigned short*)(ws + WSB_FOFF);
    half8v bfrag[4];
    #pragma unroll
    for (int c2 = 0; c2 < 4; ++c2) {
        short8v raw = *(const short8v*)(wsB + ((size_t)c2 * 64 + l) * 8);
        bfrag[c2] = *reinterpret_cast<half8v*>(&raw);
    }

    float4v acc[4];
    #pragma unroll
    for (int q = 0; q < 4; ++q) { float4v z = {0, 0, 0, 0}; acc[q] = z; }

#define COMPUTE_PASS(rr, buf)                                                   \
    {                                                                           \
        _Pragma("unroll")                                                       \
        for (int q = 0; q < 4; ++q) {                                           \
            uint4 wv = *(const uint4*)((buf) + woff[q]);                        \
            uint4 bv = *(const uint4*)((buf) + boff[q]);                        \
            __half2 d2 = d2v[q];                                                \
            uint4 afu;                                                          \
            _Pragma("unroll")                                                   \
            for (int e2 = 0; e2 < 4; ++e2) {                                    \
                unsigned wd = ((const unsigned*)&wv)[e2];                       \
                unsigned bd = ((const unsigned*)&bv)[e2];                       \
                __half2 w2 = *reinterpret_cast<__half2*>(&wd);                  \
                __half2 b2 = *reinterpret_cast<__half2*>(&bd);                  \
                __half2 tt = __hfma2(w2, d2, b2);                               \
                __half2 nt = __hmul2(tt, __hneg2(tt));   /* -(t^2) */           \
                __half2 gg = h2exp2(nt);                                        \
                ((unsigned*)&afu)[e2] = *reinterpret_cast<unsigned*>(&gg);      \
            }                                                                   \
            half8v af = *reinterpret_cast<half8v*>(&afu);                       \
            acc[q] = __builtin_amdgcn_mfma_f32_16x16x32_f16(af, bfrag[rr],      \
                                                            acc[q], 0, 0, 0);  \
        }                                                                       \
    }

    asm volatile("s_waitcnt vmcnt(0)" ::: "memory");
    __syncthreads();                 // pass-0 rows ready

    STAGE_PASS(1, bufB)              // flies under compute 0
    COMPUTE_PASS(0, bufA)
    __syncthreads();                 // drains vmcnt(0): stage-1 landed

    STAGE_PASS(2, bufA)              // flies under compute 1
    COMPUTE_PASS(1, bufB)
    __syncthreads();

    STAGE_PASS(3, bufB)              // flies under compute 2
    COMPUTE_PASS(2, bufA)
    __syncthreads();

    COMPUTE_PASS(3, bufB)
    asm volatile("s_waitcnt lgkmcnt(0)" ::: "memory");
    __syncthreads();                 // all reads done -> reuse stage as cbuf
#undef COMPUTE_PASS
#undef STAGE_PASS

    // ---- epilogue: transpose C through reused staging LDS.
    // C layout (m89): col h = l&15, row j = 16q + (l>>4)*4 + reg.
    int a_j = atoms[bi * L + t];
    int bvd = bonds[(((size_t)bi * L) + i) * L + t];
    float beh[NH];
    {
        const float4* ber = (const float4*)(bond_emb + (size_t)bvd * NH);
        #pragma unroll
        for (int u = 0; u < 4; ++u) {
            float4 v4 = ber[u];
            beh[u * 4 + 0] = v4.x; beh[u * 4 + 1] = v4.y;
            beh[u * 4 + 2] = v4.z; beh[u * 4 + 3] = v4.w;
        }
    }
    float* cbuf = (float*)(stage + (size_t)w * 4352);   // 16 x 68 floats/wave
    {
        int h = l & 15, jg = l >> 4;
        #pragma unroll
        for (int q = 0; q < 4; ++q)
            *(float4v*)(cbuf + h * 68 + q * 16 + jg * 4) = acc[q];
    }
    asm volatile("s_waitcnt lgkmcnt(0)" ::: "memory");
    __builtin_amdgcn_sched_barrier(0);

    size_t obase = (((size_t)bi * NH) * L + i) * L + t;
    // PAD column -> most-negative FINITE bf16 (0xff7f0000); survives harness bf16 cast.
    float ninf = __uint_as_float(0xff7f0000u);
    bool pad = (a_j == 0);
    #pragma unroll
    for (int h = 0; h < NH; ++h) {
        float v = cbuf[h * 68 + l] + lin_b[h] + beh[h];
        out[obase + (size_t)h * L * L] = pad ? ninf : v;
    }
}

// ================= fallback path (r6, verified) ================================
__global__ __launch_bounds__(128) void emb_kernel(const int* __restrict__ atoms,
                                                  const int* __restrict__ chirals,
                                                  const float* __restrict__ atype,
                                                  const float* __restrict__ chiral,
                                                  float* __restrict__ out) {
    int bid = blockIdx.x;
    int bi = bid >> 8, li = bid & 255;
    int a = atoms[bi * L + li];
    int c = chirals[bi * L + li];
    const float4* va = (const float4*)(atype + (size_t)a * DM);
    const float4* vc = (const float4*)(chiral + (size_t)c * DM);
    float4* vo = (float4*)(out + ((size_t)li * B + bi) * DM);
    int t = threadIdx.x;
    float4 x = va[t], y = vc[t];
    x.x += y.x; x.y += y.y; x.z += y.z; x.w += y.w;
    vo[t] = x;
}

__global__ __launch_bounds__(256) void prep_kernel(const float* __restrict__ means,
                                                   const float* __restrict__ stds,
                                                   const float* __restrict__ lin_w,
                                                   float* __restrict__ ws) {
    int t = threadIdx.x;
    const float beta = sqrtf(0.5f * 1.4426950408889634f);
    const float gscale = 0.3989422804014327f;
    if (t < APO) {
        float sigma = fabsf(stds[t]) + 1e-5f;
        float inv = 1.0f / sigma;
        ws[t] = inv * beta;
        ws[APO + t] = -means[t] * inv * beta;
    }
    unsigned short* wsB = (unsigned short*)(ws + 2 * APO);
    for (int idx = t; idx < 4 * 64 * 8; idx += 256) {
        int c2 = idx >> 9;
        int lane = (idx >> 3) & 63;
        int e = idx & 7;
        int k = c2 * 32 + ((lane >> 4) << 3) + e;
        int h = lane & 15;
        float sigma = fabsf(stds[k]) + 1e-5f;
        float v = lin_w[k * NH + h] * (gscale / sigma);
        __hip_bfloat16 hb = __float2bfloat16(v);
        wsB[idx] = *reinterpret_cast<unsigned short*>(&hb);
    }
}

__global__ __launch_bounds__(256) void pair_kernel_f32(const int* __restrict__ atoms,
                                                       const float* __restrict__ coords,
                                                       const int* __restrict__ bonds,
                                                       const float* __restrict__ wtab,
                                                       const float* __restrict__ btab,
                                                       const float* __restrict__ bond_emb,
                                                       const float* __restrict__ lin_b,
                                                       const float* __restrict__ ws,
                                                       float* __restrict__ out) {
    __shared__ float be[32][17];
    __shared__ __align__(16) char lds_raw[32 * 1024];
    __shared__ __align__(16) char lds_g[16 * 1024];

    int t = threadIdx.x;
    int bid = blockIdx.x;
    int bi = bid >> 8, i = bid & 255;
    int w = t >> 6, l = t & 63;

    for (int idx = t; idx < 32 * NH; idx += 256)
        be[idx >> 4][idx & 15] = bond_emb[idx];
    __syncthreads();

    int a_i = atoms[bi * L + i];
    int a_j = atoms[bi * L + t];

    float cix = coords[((size_t)bi * L + i) * 3 + 0];
    float ciy = coords[((size_t)bi * L + i) * 3 + 1];
    float ciz = coords[((size_t)bi * L + i) * 3 + 2];
    float cjx = coords[((size_t)bi * L + t) * 3 + 0];
    float cjy = coords[((size_t)bi * L + t) * 3 + 1];
    float cjz = coords[((size_t)bi * L + t) * 3 + 2];
    float dx = cjx - cix, dy = cjy - ciy, dz = cjz - ciz;
    float s2 = dx * dx + dy * dy + dz * dz;
    float d = (s2 > 0.0f) ? sqrtf(s2) : 0.0f;

    char* ldsW = lds_raw + (size_t)w * 8192;
    char* ldsB_ = ldsW + 4096;
    char* gbase = lds_g + (size_t)w * 4096;
    const char* wt = (const char*)wtab;
    const char* bt = (const char*)btab;
    size_t goff[4];
    #pragma unroll
    for (int q = 0; q < 4; ++q) {
        int r = q * 16 + (l >> 2);
        int ajr = atoms[bi * L + (w * 64 + r)];
        int row = ajr * VOC + a_i;
        int piece = (l & 3) ^ ((r >> 1) & 3);
        goff[q] = (size_t)row * (APO * 4) + (size_t)piece * 16;
    }
    int ss = (l >> 1) & 3;

    const float* ia = ws;
    const float* c2c = ws + APO;
    const unsigned short* wsB = (const unsigned short*)(ws + 2 * APO);
    short8v bfrag[4];
    #pragma unroll
    for (int c2 = 0; c2 < 4; ++c2)
        bfrag[c2] = *(const short8v*)(wsB + ((size_t)c2 * 64 + l) * 8);

    float4v acc[4];
    #pragma unroll
    for (int q = 0; q < 4; ++q) { float4v z = {0,0,0,0}; acc[q] = z; }

    #pragma unroll
    for (int c2i = 0; c2i < 4; ++c2i) {
        short8v g8[4];
        #pragma unroll
        for (int s = 0; s < 2; ++s) {
            int cc = c2i * 2 + s;
            #pragma unroll
            for (int q = 0; q < 4; ++q) {
                g2lds16(wt + goff[q] + cc * 64, ldsW + q * 1024);
                g2lds16(bt + goff[q] + cc * 64, ldsB_ + q * 1024);
            }
            asm volatile("s_waitcnt vmcnt(0)" ::: "memory");
            __builtin_amdgcn_sched_barrier(0);
            #pragma unroll
            for (int p = 0; p < 4; ++p) {
                int u = p ^ ss;
                float4 w4 = *(const float4*)(ldsW + l * 64 + u * 16);
                float4 b4 = *(const float4*)(ldsB_ + l * 64 + u * 16);
                const float* wp = (const float*)&w4;
                const float* bp = (const float*)&b4;
                #pragma unroll
                for (int uu = 0; uu < 4; ++uu) {
                    int kk = s * 16 + p * 4 + uu;
                    int k = c2i * 32 + kk;
                    float tt = fmaf(wp[uu], d, bp[uu]);
                    tt = fmaf(tt, ia[k], c2c[k]);
                    float g = __builtin_amdgcn_exp2f(-(tt * tt));
                    __hip_bfloat16 hb = __float2bfloat16(g);
                    g8[kk >> 3][kk & 7] = *reinterpret_cast<short*>(&hb);
                }
            }
            asm volatile("s_waitcnt lgkmcnt(0)" ::: "memory");
            __builtin_amdgcn_sched_barrier(0);
        }
        int gswz = (l >> 1) & 3;
        #pragma unroll
        for (int kg = 0; kg < 4; ++kg)
            *(short8v*)(gbase + l * 64 + ((kg ^ gswz) * 16)) = g8[kg];
        asm volatile("s_waitcnt lgkmcnt(0)" ::: "memory");
        __builtin_amdgcn_sched_barrier(0);
        #pragma unroll
        for (int q = 0; q < 4; ++q) {
            int row = q * 16 + (l & 15);
            int kgr = (l >> 4) ^ ((row >> 1) & 3);
            short8v afrag = *(const short8v*)(gbase + row * 64 + kgr * 16);
            acc[q] = __builtin_amdgcn_mfma_f32_16x16x32_bf16(afrag, bfrag[c2i], acc[q], 0, 0, 0);
        }
        asm volatile("s_waitcnt lgkmcnt(0)" ::: "memory");
        __builtin_amdgcn_sched_barrier(0);
    }

    float* cbuf = (float*)ldsW;
    {
        int h = l & 15, jg = l >> 4;
        #pragma unroll
        for (int q = 0; q < 4; ++q)
            *(float4v*)(cbuf + h * 68 + q * 16 + jg * 4) = acc[q];
    }
    asm volatile("s_waitcnt lgkmcnt(0)" ::: "memory");
    __builtin_amdgcn_sched_barrier(0);

    size_t obase = (((size_t)bi * NH) * L + i) * L + t;
    int bv = bonds[(((size_t)bi * L) + i) * L + t];
    float ninf = __uint_as_float(0xff7f0000u);
    bool pad = (a_j == 0);
    #pragma unroll
    for (int h = 0; h < NH; ++h) {
        float v = cbuf[h * 68 + l] + lin_b[h] + be[bv][h];
        out[obase + (size_t)h * L * L] = pad ? ninf : v;
    }
}

extern "C" void kernel_launch(void* const* d_in, const int* in_sizes, int n_in,
                              void* d_out, int out_size, void* d_ws, size_t ws_size,
                              hipStream_t stream) {
    const int*   atoms    = (const int*)d_in[0];
    const int*   chirals  = (const int*)d_in[1];
    const float* coords   = (const float*)d_in[2];
    const int*   bonds    = (const int*)d_in[3];
    const float* atype    = (const float*)d_in[4];
    const float* chiral   = (const float*)d_in[5];
    const float* wtab     = (const float*)d_in[6];
    const float* btab     = (const float*)d_in[7];
    const float* means    = (const float*)d_in[8];
    const float* stds     = (const float*)d_in[9];
    const float* bond_emb = (const float*)d_in[10];
    const float* lin_w    = (const float*)d_in[11];
    const float* lin_b    = (const float*)d_in[12];
    float* out = (float*)d_out;
    float* ws  = (float*)d_ws;

    if (ws_size >= WS_NEED) {
        setup_kernel<<<B * L, 256, 0, stream>>>(atoms, chirals, atype, chiral, wtab, btab,
                                                means, stds, lin_w, ws, out);
        pair_kernel_bf16<<<B * L, 256, 0, stream>>>(atoms, coords, bonds, bond_emb,
                                                    lin_b, ws, out + (size_t)EMB);
    } else {
        prep_kernel<<<1, 256, 0, stream>>>(means, stds, lin_w, ws);
        emb_kernel<<<B * L, 128, 0, stream>>>(atoms, chirals, atype, chiral, out);
        pair_kernel_f32<<<B * L, 256, 0, stream>>>(atoms, coords, bonds, wtab, btab,
                                                   bond_emb, lin_b, ws, out + (size_t)EMB);
    }
}